// Round 1
// baseline (1442.159 us; speedup 1.0000x reference)
//
#include <hip/hip_runtime.h>
#include <hip/hip_bf16.h>

#define DI __device__ __forceinline__

typedef float f32x4 __attribute__((ext_vector_type(4)));
typedef __bf16 bf16x8 __attribute__((ext_vector_type(8)));

// ---------------- workspace layout (bytes) ----------------
#define XB_OFF   0ll                      // [2048][8][8][512] bf16  = 134217728
#define W1_OFF   134217728ll              // [768][4608] bf16        = 7077888
#define W2_OFF   141295616ll              // [768][2304] bf16        = 3538944
#define Y1_OFF   144834560ll              // [73728][768] bf16       = 113246208
#define QKV_OFF  258080768ll              // 3 x [32768][256] bf16   = 50331648
#define SEG_OFF  308412416ll              // 18 ints
// aliases inside the Y1 region (only used after conv2 is done):
#define S_OFF    (Y1_OFF)                 // [2048][2048] f32  = 16777216
#define P_OFF    (Y1_OFF + 16777216ll)    // [2048][2048] bf16 = 8388608
#define VT_OFF   (Y1_OFF + 25165824ll)    // [4096][2048] bf16 = 16777216

DI unsigned short f2bf(float f) {
  union { float f; unsigned u; } v; v.f = f;
  return (unsigned short)((v.u + 0x7FFFu + ((v.u >> 16) & 1u)) >> 16);
}

// async global->LDS, 16B per lane; LDS dest must be wave-uniform base (lane*16 implicit)
DI void stage16(const void* g, void* l) {
  __builtin_amdgcn_global_load_lds(
      (const __attribute__((address_space(1))) void*)(unsigned long long)g,
      (__attribute__((address_space(3))) void*)(unsigned long long)l,
      16, 0, 0);
}

// one BK=32 step: 8 ds_read_b128 + 16 MFMA per wave.
// LDS tiles: [128 rows][4 x 16B chunks], chunk XOR-swizzled by (row&3) -> 2-way conflicts (free).
DI void mma_step(const unsigned short* lA, const unsigned short* lB,
                 f32x4 acc[4][4], int lane, int wm, int wn) {
  const int r15 = lane & 15;
  const int ph = (lane >> 4) ^ (lane & 3);
  bf16x8 af[4], bfr[4];
#pragma unroll
  for (int mi = 0; mi < 4; mi++)
    af[mi] = *(const bf16x8*)(lA + (wm * 64 + mi * 16 + r15) * 32 + ph * 8);
#pragma unroll
  for (int ni = 0; ni < 4; ni++)
    bfr[ni] = *(const bf16x8*)(lB + (wn * 64 + ni * 16 + r15) * 32 + ph * 8);
#pragma unroll
  for (int mi = 0; mi < 4; mi++)
#pragma unroll
    for (int ni = 0; ni < 4; ni++)
      acc[mi][ni] = __builtin_amdgcn_mfma_f32_16x16x32_bf16(af[mi], bfr[ni], acc[mi][ni], 0, 0, 0);
}

// ---------------- segment offsets (+ int32/int64 layout detect) ----------------
__global__ void k_seg(const int* __restrict__ gid, int* __restrict__ seg) {
  __shared__ int cnt[16];
  int tid = threadIdx.x;
  if (tid < 16) cnt[tid] = 0;
  __syncthreads();
  // if harness passed int64 data, the int32 view is [val,0,val,0,...]; sorted ids
  // make gid32[2047] == 0 essentially impossible in int32 layout.
  int stride = (gid[2047] == 0) ? 2 : 1;
  for (int i = tid; i < 2048; i += 256) atomicAdd(&cnt[gid[i * stride]], 1);
  __syncthreads();
  if (tid == 0) {
    int s = 0;
    for (int g = 0; g < 16; g++) { seg[g] = s; s += cnt[g]; }
    seg[16] = s;
    seg[17] = stride;
  }
}

// ---------------- NCHW f32 -> NHWC bf16 ----------------
__global__ void k_convert_x(const float* __restrict__ x, unsigned short* __restrict__ xb) {
  __shared__ unsigned short t[32][66];
  const int n = blockIdx.x, cb = blockIdx.y;   // cb*32 channel base
  const int tid = threadIdx.x;
  const int cr = tid >> 6, p = tid & 63;
  const float* src = x + (n * 512 + cb * 32) * 64;
#pragma unroll
  for (int i = 0; i < 8; i++) {
    int c = i * 4 + cr;
    t[c][p] = f2bf(src[c * 64 + p]);
  }
  __syncthreads();
  unsigned short* dst = xb + n * 32768 + cb * 32;
  const int pr = tid >> 5, c2 = tid & 31;
#pragma unroll
  for (int i = 0; i < 8; i++) {
    int p2 = i * 8 + pr;
    dst[p2 * 512 + c2] = t[c2][p2];
  }
}

// ---------------- weights: OIHW f32 -> [768][(ky,kx,cin)] bf16 ----------------
__global__ void k_convert_w1(const float* __restrict__ qw, const float* __restrict__ kw,
                             const float* __restrict__ vw, unsigned short* __restrict__ w1t) {
  int idx = blockIdx.x * 256 + threadIdx.x;    // 768*4608
  int row = idx / 4608, k = idx - row * 4608;
  int br = row >> 8, o = row & 255;
  int kk = k >> 9, cin = k & 511;
  int ky = kk / 3, kx = kk - ky * 3;
  const float* w = (br == 0) ? qw : (br == 1) ? kw : vw;
  w1t[idx] = f2bf(w[((o * 512 + cin) * 3 + ky) * 3 + kx]);
}

__global__ void k_convert_w2(const float* __restrict__ qw, const float* __restrict__ kw,
                             const float* __restrict__ vw, unsigned short* __restrict__ w2t) {
  int idx = blockIdx.x * 256 + threadIdx.x;    // 768*2304
  int row = idx / 2304, k = idx - row * 2304;
  int br = row >> 8, o = row & 255;
  int kk = k >> 8, c = k & 255;
  int ky = kk / 3, kx = kk - ky * 3;
  const float* w = (br == 0) ? qw : (br == 1) ? kw : vw;
  w2t[idx] = f2bf(w[((o * 256 + c) * 3 + ky) * 3 + kx]);
}

// ---------------- conv1 implicit GEMM: M=73728 K=4608 N=768 ----------------
__global__ __launch_bounds__(256, 2) void k_conv1(
    const unsigned short* __restrict__ xb, const unsigned short* __restrict__ w1t,
    const float* __restrict__ qb1, const float* __restrict__ kb1, const float* __restrict__ vb1,
    unsigned short* __restrict__ y1) {
  __shared__ __align__(16) unsigned short lA[128 * 32];
  __shared__ __align__(16) unsigned short lB[128 * 32];
  const int mt = blockIdx.x, nt = blockIdx.y;
  const int tid = threadIdx.x;
  const int wave = tid >> 6, lane = tid & 63;
  const int wm = wave >> 1, wn = wave & 1;

  const int srow = wave * 32 + (lane >> 2);
  const int clog = (lane & 3) ^ ((lane >> 2) & 3);   // logical chunk for this phys slot
  const unsigned short* ap[2];
  const unsigned short* bp[2];
#pragma unroll
  for (int h = 0; h < 2; h++) {
    int m = mt * 128 + srow + h * 16;
    int n = m / 36, pix = m - n * 36;
    int oy = pix / 6, ox = pix - oy * 6;
    ap[h] = xb + ((n * 8 + oy) * 8 + ox) * 512 + clog * 8;
    int r = nt * 128 + srow + h * 16;
    bp[h] = w1t + r * 4608 + clog * 8;
  }
  unsigned short* la0 = lA + (wave * 32) * 32;
  unsigned short* la1 = lA + (wave * 32 + 16) * 32;
  unsigned short* lb0 = lB + (wave * 32) * 32;
  unsigned short* lb1 = lB + (wave * 32 + 16) * 32;

  f32x4 acc[4][4];
  const f32x4 z = {0.f, 0.f, 0.f, 0.f};
#pragma unroll
  for (int i = 0; i < 4; i++)
#pragma unroll
    for (int j = 0; j < 4; j++) acc[i][j] = z;

  for (int kt = 0; kt < 144; kt++) {
    int kk = kt >> 4;
    int ky = kk / 3, kx = kk - ky * 3;
    int aoff = (ky * 8 + kx) * 512 + (kt & 15) * 32;
    int boff = kt * 32;
    __syncthreads();
    stage16(ap[0] + aoff, la0);
    stage16(ap[1] + aoff, la1);
    stage16(bp[0] + boff, lb0);
    stage16(bp[1] + boff, lb1);
    __syncthreads();
    mma_step(lA, lB, acc, lane, wm, wn);
  }

  const float* bias = (nt < 2) ? qb1 : (nt < 4) ? kb1 : vb1;
  const int r15 = lane & 15, q4 = lane >> 4;
#pragma unroll
  for (int ni = 0; ni < 4; ni++) {
    int col = nt * 128 + wn * 64 + ni * 16 + r15;
    float bv = bias[col & 255];
#pragma unroll
    for (int mi = 0; mi < 4; mi++) {
      int m0 = mt * 128 + wm * 64 + mi * 16 + q4 * 4;
#pragma unroll
      for (int r = 0; r < 4; r++) {
        float v = acc[mi][ni][r] + bv;
        y1[(m0 + r) * 768 + col] = f2bf(v > 0.f ? v : 0.f);
      }
    }
  }
}

// ---------------- conv2 implicit GEMM per branch: M=32768 K=2304 N=256 ----------------
__global__ __launch_bounds__(256, 2) void k_conv2(
    const unsigned short* __restrict__ y1, const unsigned short* __restrict__ w2t,
    const float* __restrict__ qb2, const float* __restrict__ kb2, const float* __restrict__ vb2,
    unsigned short* __restrict__ qkv) {
  __shared__ __align__(16) unsigned short lA[128 * 32];
  __shared__ __align__(16) unsigned short lB[128 * 32];
  const int mt = blockIdx.x, nt = blockIdx.y, br = blockIdx.z;
  const int tid = threadIdx.x;
  const int wave = tid >> 6, lane = tid & 63;
  const int wm = wave >> 1, wn = wave & 1;

  const int srow = wave * 32 + (lane >> 2);
  const int clog = (lane & 3) ^ ((lane >> 2) & 3);
  const unsigned short* ap[2];
  const unsigned short* bp[2];
#pragma unroll
  for (int h = 0; h < 2; h++) {
    int m = mt * 128 + srow + h * 16;
    int n = m >> 4, pix = m & 15;
    int oy = pix >> 2, ox = pix & 3;
    ap[h] = y1 + (n * 36 + oy * 6 + ox) * 768 + br * 256 + clog * 8;
    int r = br * 256 + nt * 128 + srow + h * 16;
    bp[h] = w2t + r * 2304 + clog * 8;
  }
  unsigned short* la0 = lA + (wave * 32) * 32;
  unsigned short* la1 = lA + (wave * 32 + 16) * 32;
  unsigned short* lb0 = lB + (wave * 32) * 32;
  unsigned short* lb1 = lB + (wave * 32 + 16) * 32;

  f32x4 acc[4][4];
  const f32x4 z = {0.f, 0.f, 0.f, 0.f};
#pragma unroll
  for (int i = 0; i < 4; i++)
#pragma unroll
    for (int j = 0; j < 4; j++) acc[i][j] = z;

  for (int kt = 0; kt < 72; kt++) {
    int kk = kt >> 3;
    int ky = kk / 3, kx = kk - ky * 3;
    int aoff = (ky * 6 + kx) * 768 + (kt & 7) * 32;
    int boff = kt * 32;
    __syncthreads();
    stage16(ap[0] + aoff, la0);
    stage16(ap[1] + aoff, la1);
    stage16(bp[0] + boff, lb0);
    stage16(bp[1] + boff, lb1);
    __syncthreads();
    mma_step(lA, lB, acc, lane, wm, wn);
  }

  const float* bias = (br == 0) ? qb2 : (br == 1) ? kb2 : vb2;
  unsigned short* outb = qkv + br * 8388608;
  const int r15 = lane & 15, q4 = lane >> 4;
#pragma unroll
  for (int ni = 0; ni < 4; ni++) {
    int o = nt * 128 + wn * 64 + ni * 16 + r15;
    float bv = bias[o];
#pragma unroll
    for (int mi = 0; mi < 4; mi++) {
      int m0 = mt * 128 + wm * 64 + mi * 16 + q4 * 4;
#pragma unroll
      for (int r = 0; r < 4; r++) {
        float v = acc[mi][ni][r] + bv;
        outb[(m0 + r) * 256 + o] = f2bf(v > 0.f ? v : 0.f);
      }
    }
  }
}

// ---------------- S = Q @ K^T, only block-diagonal-overlapping tiles ----------------
__global__ __launch_bounds__(256, 2) void k_scores(
    const unsigned short* __restrict__ qf, const unsigned short* __restrict__ kf,
    const int* __restrict__ gid, const int* __restrict__ seg, float* __restrict__ S) {
  const int mt = blockIdx.x, jt = blockIdx.y;
  const int stride = seg[17];
  const int g_lo = gid[(mt * 128) * stride], g_hi = gid[(mt * 128 + 127) * stride];
  const int jlo = seg[g_lo], jhi = seg[g_hi + 1];
  if (jt * 128 >= jhi || jt * 128 + 128 <= jlo) return;

  __shared__ __align__(16) unsigned short lA[128 * 32];
  __shared__ __align__(16) unsigned short lB[128 * 32];
  const int tid = threadIdx.x;
  const int wave = tid >> 6, lane = tid & 63;
  const int wm = wave >> 1, wn = wave & 1;
  const int srow = wave * 32 + (lane >> 2);
  const int clog = (lane & 3) ^ ((lane >> 2) & 3);
  const unsigned short* ap[2];
  const unsigned short* bp[2];
#pragma unroll
  for (int h = 0; h < 2; h++) {
    ap[h] = qf + (mt * 128 + srow + h * 16) * 4096 + clog * 8;
    bp[h] = kf + (jt * 128 + srow + h * 16) * 4096 + clog * 8;
  }
  unsigned short* la0 = lA + (wave * 32) * 32;
  unsigned short* la1 = lA + (wave * 32 + 16) * 32;
  unsigned short* lb0 = lB + (wave * 32) * 32;
  unsigned short* lb1 = lB + (wave * 32 + 16) * 32;

  f32x4 acc[4][4];
  const f32x4 z = {0.f, 0.f, 0.f, 0.f};
#pragma unroll
  for (int i = 0; i < 4; i++)
#pragma unroll
    for (int j = 0; j < 4; j++) acc[i][j] = z;

  for (int kt = 0; kt < 128; kt++) {
    int off = kt * 32;
    __syncthreads();
    stage16(ap[0] + off, la0);
    stage16(ap[1] + off, la1);
    stage16(bp[0] + off, lb0);
    stage16(bp[1] + off, lb1);
    __syncthreads();
    mma_step(lA, lB, acc, lane, wm, wn);
  }

  const int r15 = lane & 15, q4 = lane >> 4;
#pragma unroll
  for (int ni = 0; ni < 4; ni++) {
    int j = jt * 128 + wn * 64 + ni * 16 + r15;
#pragma unroll
    for (int mi = 0; mi < 4; mi++) {
      int m0 = mt * 128 + wm * 64 + mi * 16 + q4 * 4;
#pragma unroll
      for (int r = 0; r < 4; r++)
        S[(m0 + r) * 2048 + j] = acc[mi][ni][r];
    }
  }
}

// ---------------- per-row masked softmax -> P (bf16) ----------------
__global__ void k_softmax(const float* __restrict__ S, const int* __restrict__ gid,
                          const int* __restrict__ seg, unsigned short* __restrict__ P) {
  const int m = blockIdx.x * 4 + (threadIdx.x >> 6);
  const int lane = threadIdx.x & 63;
  const int stride = seg[17];
  const int g = gid[m * stride];
  const int s0 = seg[g], e = seg[g + 1];
  const float scale = 0.04419417382415922f;   // 1/sqrt(512)
  const float* row = S + m * 2048;
  float mx = -3.0e38f;
  for (int j = s0 + lane; j < e; j += 64) mx = fmaxf(mx, row[j]);
#pragma unroll
  for (int off = 32; off > 0; off >>= 1) mx = fmaxf(mx, __shfl_xor(mx, off));
  float sum = 0.f;
  for (int j = s0 + lane; j < e; j += 64) sum += __expf((row[j] - mx) * scale);
#pragma unroll
  for (int off = 32; off > 0; off >>= 1) sum += __shfl_xor(sum, off);
  const float inv = 1.f / sum;
  unsigned short* prow = P + m * 2048;
  for (int j = s0 + lane; j < e; j += 64)
    prow[j] = f2bf(__expf((row[j] - mx) * scale) * inv);
}

// ---------------- vf [2048][4096] -> vT [4096][2048] ----------------
__global__ void k_transpose_v(const unsigned short* __restrict__ vf,
                              unsigned short* __restrict__ vT) {
  __shared__ unsigned short t[64][66];
  const int jt = blockIdx.x, dt = blockIdx.y;
  const int tid = threadIdx.x;
  const int r = tid >> 6, c = tid & 63;
#pragma unroll
  for (int i = 0; i < 16; i++) {
    int j = i * 4 + r;
    t[j][c] = vf[(jt * 64 + j) * 4096 + dt * 64 + c];
  }
  __syncthreads();
#pragma unroll
  for (int i = 0; i < 16; i++) {
    int d = i * 4 + r;
    vT[(dt * 64 + d) * 2048 + jt * 64 + c] = t[c][d];
  }
}

// ---------------- out = P @ V (ragged K per m-tile), epilogue -> NCHW f32 ----------------
__global__ __launch_bounds__(256, 2) void k_pv(
    const unsigned short* __restrict__ P, const unsigned short* __restrict__ vT,
    const int* __restrict__ gid, const int* __restrict__ seg, float* __restrict__ out) {
  const int mt = blockIdx.x, dt = blockIdx.y;
  const int stride = seg[17];
  const int g_lo = gid[(mt * 128) * stride], g_hi = gid[(mt * 128 + 127) * stride];
  const int ks0 = seg[g_lo] & ~31;
  const int ke = seg[g_hi + 1];
  const int iters = (ke - ks0 + 31) >> 5;   // P==0 outside segments covers padding

  __shared__ __align__(16) unsigned short lA[128 * 32];
  __shared__ __align__(16) unsigned short lB[128 * 32];
  const int tid = threadIdx.x;
  const int wave = tid >> 6, lane = tid & 63;
  const int wm = wave >> 1, wn = wave & 1;
  const int srow = wave * 32 + (lane >> 2);
  const int clog = (lane & 3) ^ ((lane >> 2) & 3);
  const unsigned short* ap[2];
  const unsigned short* bp[2];
#pragma unroll
  for (int h = 0; h < 2; h++) {
    ap[h] = P + (mt * 128 + srow + h * 16) * 2048 + ks0 + clog * 8;
    bp[h] = vT + (dt * 128 + srow + h * 16) * 2048 + ks0 + clog * 8;
  }
  unsigned short* la0 = lA + (wave * 32) * 32;
  unsigned short* la1 = lA + (wave * 32 + 16) * 32;
  unsigned short* lb0 = lB + (wave * 32) * 32;
  unsigned short* lb1 = lB + (wave * 32 + 16) * 32;

  f32x4 acc[4][4];
  const f32x4 z = {0.f, 0.f, 0.f, 0.f};
#pragma unroll
  for (int i = 0; i < 4; i++)
#pragma unroll
    for (int j = 0; j < 4; j++) acc[i][j] = z;

  for (int kt = 0; kt < iters; kt++) {
    int off = kt * 32;
    __syncthreads();
    stage16(ap[0] + off, la0);
    stage16(ap[1] + off, la1);
    stage16(bp[0] + off, lb0);
    stage16(bp[1] + off, lb1);
    __syncthreads();
    mma_step(lA, lB, acc, lane, wm, wn);
  }

  const int r15 = lane & 15, q4 = lane >> 4;
#pragma unroll
  for (int ni = 0; ni < 4; ni++) {
    int d = dt * 128 + wn * 64 + ni * 16 + r15;
    int c = d & 255, pix = d >> 8;   // our d = pix*256 + c; ref wants n*4096 + c*16 + pix
#pragma unroll
    for (int mi = 0; mi < 4; mi++) {
      int m0 = mt * 128 + wm * 64 + mi * 16 + q4 * 4;
#pragma unroll
      for (int r = 0; r < 4; r++)
        out[(m0 + r) * 4096 + c * 16 + pix] = acc[mi][ni][r];
    }
  }
}

extern "C" void kernel_launch(void* const* d_in, const int* in_sizes, int n_in,
                              void* d_out, int out_size, void* d_ws, size_t ws_size,
                              hipStream_t stream) {
  const float* x   = (const float*)d_in[0];
  const int*   gid = (const int*)d_in[1];
  const float* qw1 = (const float*)d_in[2];
  const float* qb1 = (const float*)d_in[3];
  const float* qw2 = (const float*)d_in[4];
  const float* qb2 = (const float*)d_in[5];
  const float* kw1 = (const float*)d_in[6];
  const float* kb1 = (const float*)d_in[7];
  const float* kw2 = (const float*)d_in[8];
  const float* kb2 = (const float*)d_in[9];
  const float* vw1 = (const float*)d_in[10];
  const float* vb1 = (const float*)d_in[11];
  const float* vw2 = (const float*)d_in[12];
  const float* vb2 = (const float*)d_in[13];

  char* ws = (char*)d_ws;
  unsigned short* xb  = (unsigned short*)(ws + XB_OFF);
  unsigned short* w1t = (unsigned short*)(ws + W1_OFF);
  unsigned short* w2t = (unsigned short*)(ws + W2_OFF);
  unsigned short* y1  = (unsigned short*)(ws + Y1_OFF);
  unsigned short* qkv = (unsigned short*)(ws + QKV_OFF);
  int* seg            = (int*)(ws + SEG_OFF);
  float* S            = (float*)(ws + S_OFF);
  unsigned short* P   = (unsigned short*)(ws + P_OFF);
  unsigned short* vT  = (unsigned short*)(ws + VT_OFF);
  const unsigned short* qf = qkv;
  const unsigned short* kf = qkv + 8388608;
  const unsigned short* vf = qkv + 16777216;

  k_seg<<<1, 256, 0, stream>>>(gid, seg);
  k_convert_x<<<dim3(2048, 16), 256, 0, stream>>>(x, xb);
  k_convert_w1<<<13824, 256, 0, stream>>>(qw1, kw1, vw1, w1t);
  k_convert_w2<<<6912, 256, 0, stream>>>(qw2, kw2, vw2, w2t);
  k_conv1<<<dim3(576, 6), 256, 0, stream>>>(xb, w1t, qb1, kb1, vb1, y1);
  k_conv2<<<dim3(256, 2, 3), 256, 0, stream>>>(y1, w2t, qb2, kb2, vb2, qkv);
  hipMemsetAsync(P, 0, 8388608, stream);   // P zero outside segments (S/P/vT alias dead y1)
  k_scores<<<dim3(16, 16), 256, 0, stream>>>(qf, kf, gid, seg, S);
  k_softmax<<<512, 256, 0, stream>>>(S, gid, seg, P);
  k_transpose_v<<<dim3(32, 64), 256, 0, stream>>>(vf, vT);
  k_pv<<<dim3(16, 32), 256, 0, stream>>>(P, vT, gid, seg, (float*)d_out);
}

// Round 2
// 1385.607 us; speedup vs baseline: 1.0408x; 1.0408x over previous
//
#include <hip/hip_runtime.h>
#include <hip/hip_bf16.h>

#define DI __device__ __forceinline__

typedef float f32x4 __attribute__((ext_vector_type(4)));
typedef __bf16 bf16x8 __attribute__((ext_vector_type(8)));

// ---------------- workspace layout (bytes) ----------------
#define XB_OFF   0ll                      // [2048][8][8][512] bf16  = 134217728
#define W1_OFF   134217728ll              // [768][4608] bf16        = 7077888
#define W2_OFF   141295616ll              // [768][2304] bf16        = 3538944
#define Y1_OFF   144834560ll              // [73728][768] bf16       = 113246208
#define QKV_OFF  258080768ll              // 3 x [32768][256] bf16   = 50331648
#define SEG_OFF  308412416ll              // 18 ints
// aliases inside the Y1 region (only used after conv2 is done):
#define S_OFF    (Y1_OFF)                 // 4 x [2048][2048] f32 = 67108864
#define P_OFF    (Y1_OFF + 67108864ll)    // [2048][2048] bf16    = 8388608
#define VT_OFF   (Y1_OFF + 75497472ll)    // [4096][2048] bf16    = 16777216

DI unsigned short f2bf(float f) {
  union { float f; unsigned u; } v; v.f = f;
  return (unsigned short)((v.u + 0x7FFFu + ((v.u >> 16) & 1u)) >> 16);
}

// async global->LDS, 16B per lane; LDS dest is wave-uniform base + lane*16
DI void stage16(const void* g, void* l) {
  __builtin_amdgcn_global_load_lds(
      (const __attribute__((address_space(1))) void*)(unsigned long long)g,
      (__attribute__((address_space(3))) void*)(unsigned long long)l,
      16, 0, 0);
}

// Swizzle: physical chunk p of row r holds logical chunk p ^ ((r>>1)&3).
// Staging lane l covers row (l>>2): clog = (l&3) ^ ((l>>3)&3).
// Read lane l wants logical chunk (l>>4) of row (l&15): ph = (l>>4) ^ ((l>>1)&3).
// Bank group (4*(r&1)+p) mod 8 is then a bijection over each 8-lane group ->
// conflict-free ds_read_b128 (was 4-way conflict with the old row&3 swizzle).
DI void mma_step(const unsigned short* lA, const unsigned short* lB,
                 f32x4 acc[4][4], int lane, int wm, int wn) {
  const int r15 = lane & 15;
  const int ph = (lane >> 4) ^ ((lane >> 1) & 3);
  bf16x8 af[4], bfr[4];
#pragma unroll
  for (int mi = 0; mi < 4; mi++)
    af[mi] = *(const bf16x8*)(lA + (wm * 64 + mi * 16 + r15) * 32 + ph * 8);
#pragma unroll
  for (int ni = 0; ni < 4; ni++)
    bfr[ni] = *(const bf16x8*)(lB + (wn * 64 + ni * 16 + r15) * 32 + ph * 8);
#pragma unroll
  for (int mi = 0; mi < 4; mi++)
#pragma unroll
    for (int ni = 0; ni < 4; ni++)
      acc[mi][ni] = __builtin_amdgcn_mfma_f32_16x16x32_bf16(af[mi], bfr[ni], acc[mi][ni], 0, 0, 0);
}

// ---------------- segment offsets (+ int32/int64 layout detect) ----------------
__global__ void k_seg(const int* __restrict__ gid, int* __restrict__ seg) {
  __shared__ int cnt[16];
  int tid = threadIdx.x;
  if (tid < 16) cnt[tid] = 0;
  __syncthreads();
  int stride = (gid[2047] == 0) ? 2 : 1;
  for (int i = tid; i < 2048; i += 256) atomicAdd(&cnt[gid[i * stride]], 1);
  __syncthreads();
  if (tid == 0) {
    int s = 0;
    for (int g = 0; g < 16; g++) { seg[g] = s; s += cnt[g]; }
    seg[16] = s;
    seg[17] = stride;
  }
}

// ---------------- NCHW f32 -> NHWC bf16 (64-channel blocks, uint stores) ----------------
__global__ void k_convert_x(const float* __restrict__ x, unsigned short* __restrict__ xb) {
  __shared__ unsigned short t[64][66];   // [pixel][channel]
  const int n = blockIdx.x, cb = blockIdx.y;   // cb*64 channel base
  const int tid = threadIdx.x;
  const int cr = tid >> 6, p = tid & 63;
  const float* src = x + (n * 512 + cb * 64) * 64;
#pragma unroll
  for (int i = 0; i < 16; i++) {
    int c = i * 4 + cr;
    t[p][c] = f2bf(src[c * 64 + p]);
  }
  __syncthreads();
  unsigned* dst = (unsigned*)(xb + n * 32768 + cb * 64);   // 256-uint pixel stride
  const int pr = tid >> 5, c2 = tid & 31;
#pragma unroll
  for (int i = 0; i < 8; i++) {
    int p2 = i * 8 + pr;
    unsigned lo = t[p2][c2 * 2], hi = t[p2][c2 * 2 + 1];
    dst[p2 * 256 + c2] = lo | (hi << 16);
  }
}

// ---------------- weights: OIHW f32 -> [row][(ky,kx,cin)] bf16, fused w1+w2 ----------------
__global__ void k_convert_w(const float* __restrict__ qw1, const float* __restrict__ kw1,
                            const float* __restrict__ vw1, const float* __restrict__ qw2,
                            const float* __restrict__ kw2, const float* __restrict__ vw2,
                            unsigned short* __restrict__ w1t, unsigned short* __restrict__ w2t) {
  int idx = blockIdx.x * 256 + threadIdx.x;
  if (idx < 3538944) {                       // w1: 768 x 4608
    int row = idx / 4608, k = idx - row * 4608;
    int br = row >> 8, o = row & 255;
    int kk = k >> 9, cin = k & 511;
    int ky = kk / 3, kx = kk - ky * 3;
    const float* w = (br == 0) ? qw1 : (br == 1) ? kw1 : vw1;
    w1t[idx] = f2bf(w[((o * 512 + cin) * 3 + ky) * 3 + kx]);
  } else {                                   // w2: 768 x 2304
    idx -= 3538944;
    int row = idx / 2304, k = idx - row * 2304;
    int br = row >> 8, o = row & 255;
    int kk = k >> 8, c = k & 255;
    int ky = kk / 3, kx = kk - ky * 3;
    const float* w = (br == 0) ? qw2 : (br == 1) ? kw2 : vw2;
    w2t[idx] = f2bf(w[((o * 256 + c) * 3 + ky) * 3 + kx]);
  }
}

// ---------------- conv1 implicit GEMM: M=73728 K=4608 N=768 ----------------
__global__ __launch_bounds__(256, 2) void k_conv1(
    const unsigned short* __restrict__ xb, const unsigned short* __restrict__ w1t,
    const float* __restrict__ qb1, const float* __restrict__ kb1, const float* __restrict__ vb1,
    unsigned short* __restrict__ y1) {
  __shared__ __align__(16) unsigned short lA[128 * 32];
  __shared__ __align__(16) unsigned short lB[128 * 32];
  const int mt = blockIdx.x, nt = blockIdx.y;
  const int tid = threadIdx.x;
  const int wave = tid >> 6, lane = tid & 63;
  const int wm = wave >> 1, wn = wave & 1;

  const int srow = wave * 32 + (lane >> 2);
  const int clog = (lane & 3) ^ ((lane >> 3) & 3);
  const unsigned short* ap[2];
  const unsigned short* bp[2];
#pragma unroll
  for (int h = 0; h < 2; h++) {
    int m = mt * 128 + srow + h * 16;
    int n = m / 36, pix = m - n * 36;
    int oy = pix / 6, ox = pix - oy * 6;
    ap[h] = xb + ((n * 8 + oy) * 8 + ox) * 512 + clog * 8;
    int r = nt * 128 + srow + h * 16;
    bp[h] = w1t + r * 4608 + clog * 8;
  }
  unsigned short* la0 = lA + (wave * 32) * 32;
  unsigned short* la1 = lA + (wave * 32 + 16) * 32;
  unsigned short* lb0 = lB + (wave * 32) * 32;
  unsigned short* lb1 = lB + (wave * 32 + 16) * 32;

  f32x4 acc[4][4];
  const f32x4 z = {0.f, 0.f, 0.f, 0.f};
#pragma unroll
  for (int i = 0; i < 4; i++)
#pragma unroll
    for (int j = 0; j < 4; j++) acc[i][j] = z;

  for (int kt = 0; kt < 144; kt++) {
    int kk = kt >> 4;
    int ky = kk / 3, kx = kk - ky * 3;
    int aoff = (ky * 8 + kx) * 512 + (kt & 15) * 32;
    int boff = kt * 32;
    __syncthreads();
    stage16(ap[0] + aoff, la0);
    stage16(ap[1] + aoff, la1);
    stage16(bp[0] + boff, lb0);
    stage16(bp[1] + boff, lb1);
    __syncthreads();
    mma_step(lA, lB, acc, lane, wm, wn);
  }

  const float* bias = (nt < 2) ? qb1 : (nt < 4) ? kb1 : vb1;
  const int r15 = lane & 15, q4 = lane >> 4;
#pragma unroll
  for (int ni = 0; ni < 4; ni++) {
    int col = nt * 128 + wn * 64 + ni * 16 + r15;
    float bv = bias[col & 255];
#pragma unroll
    for (int mi = 0; mi < 4; mi++) {
      int m0 = mt * 128 + wm * 64 + mi * 16 + q4 * 4;
#pragma unroll
      for (int r = 0; r < 4; r++) {
        float v = acc[mi][ni][r] + bv;
        y1[(m0 + r) * 768 + col] = f2bf(v > 0.f ? v : 0.f);
      }
    }
  }
}

// ---------------- conv2 implicit GEMM per branch: M=32768 K=2304 N=256 ----------------
__global__ __launch_bounds__(256, 2) void k_conv2(
    const unsigned short* __restrict__ y1, const unsigned short* __restrict__ w2t,
    const float* __restrict__ qb2, const float* __restrict__ kb2, const float* __restrict__ vb2,
    unsigned short* __restrict__ qkv) {
  __shared__ __align__(16) unsigned short lA[128 * 32];
  __shared__ __align__(16) unsigned short lB[128 * 32];
  const int mt = blockIdx.x, nt = blockIdx.y, br = blockIdx.z;
  const int tid = threadIdx.x;
  const int wave = tid >> 6, lane = tid & 63;
  const int wm = wave >> 1, wn = wave & 1;

  const int srow = wave * 32 + (lane >> 2);
  const int clog = (lane & 3) ^ ((lane >> 3) & 3);
  const unsigned short* ap[2];
  const unsigned short* bp[2];
#pragma unroll
  for (int h = 0; h < 2; h++) {
    int m = mt * 128 + srow + h * 16;
    int n = m >> 4, pix = m & 15;
    int oy = pix >> 2, ox = pix & 3;
    ap[h] = y1 + (n * 36 + oy * 6 + ox) * 768 + br * 256 + clog * 8;
    int r = br * 256 + nt * 128 + srow + h * 16;
    bp[h] = w2t + r * 2304 + clog * 8;
  }
  unsigned short* la0 = lA + (wave * 32) * 32;
  unsigned short* la1 = lA + (wave * 32 + 16) * 32;
  unsigned short* lb0 = lB + (wave * 32) * 32;
  unsigned short* lb1 = lB + (wave * 32 + 16) * 32;

  f32x4 acc[4][4];
  const f32x4 z = {0.f, 0.f, 0.f, 0.f};
#pragma unroll
  for (int i = 0; i < 4; i++)
#pragma unroll
    for (int j = 0; j < 4; j++) acc[i][j] = z;

  for (int kt = 0; kt < 72; kt++) {
    int kk = kt >> 3;
    int ky = kk / 3, kx = kk - ky * 3;
    int aoff = (ky * 6 + kx) * 768 + (kt & 7) * 32;
    int boff = kt * 32;
    __syncthreads();
    stage16(ap[0] + aoff, la0);
    stage16(ap[1] + aoff, la1);
    stage16(bp[0] + boff, lb0);
    stage16(bp[1] + boff, lb1);
    __syncthreads();
    mma_step(lA, lB, acc, lane, wm, wn);
  }

  const float* bias = (br == 0) ? qb2 : (br == 1) ? kb2 : vb2;
  unsigned short* outb = qkv + br * 8388608;
  const int r15 = lane & 15, q4 = lane >> 4;
#pragma unroll
  for (int ni = 0; ni < 4; ni++) {
    int o = nt * 128 + wn * 64 + ni * 16 + r15;
    float bv = bias[o];
#pragma unroll
    for (int mi = 0; mi < 4; mi++) {
      int m0 = mt * 128 + wm * 64 + mi * 16 + q4 * 4;
#pragma unroll
      for (int r = 0; r < 4; r++) {
        float v = acc[mi][ni][r] + bv;
        outb[(m0 + r) * 256 + o] = f2bf(v > 0.f ? v : 0.f);
      }
    }
  }
}

// ---------------- S_part[ks] = Q @ K^T over K-chunk ks (4-way K-split) ----------------
__global__ __launch_bounds__(256, 2) void k_scores(
    const unsigned short* __restrict__ qf, const unsigned short* __restrict__ kf,
    const int* __restrict__ gid, const int* __restrict__ seg, float* __restrict__ S) {
  const int mt = blockIdx.x, jt = blockIdx.y, ks = blockIdx.z;
  const int stride = seg[17];
  const int g_lo = gid[(mt * 128) * stride], g_hi = gid[(mt * 128 + 127) * stride];
  const int jlo = seg[g_lo], jhi = seg[g_hi + 1];
  if (jt * 128 >= jhi || jt * 128 + 128 <= jlo) return;

  __shared__ __align__(16) unsigned short lA[128 * 32];
  __shared__ __align__(16) unsigned short lB[128 * 32];
  const int tid = threadIdx.x;
  const int wave = tid >> 6, lane = tid & 63;
  const int wm = wave >> 1, wn = wave & 1;
  const int srow = wave * 32 + (lane >> 2);
  const int clog = (lane & 3) ^ ((lane >> 3) & 3);
  const unsigned short* ap[2];
  const unsigned short* bp[2];
#pragma unroll
  for (int h = 0; h < 2; h++) {
    ap[h] = qf + (mt * 128 + srow + h * 16) * 4096 + clog * 8;
    bp[h] = kf + (jt * 128 + srow + h * 16) * 4096 + clog * 8;
  }
  unsigned short* la0 = lA + (wave * 32) * 32;
  unsigned short* la1 = lA + (wave * 32 + 16) * 32;
  unsigned short* lb0 = lB + (wave * 32) * 32;
  unsigned short* lb1 = lB + (wave * 32 + 16) * 32;

  f32x4 acc[4][4];
  const f32x4 z = {0.f, 0.f, 0.f, 0.f};
#pragma unroll
  for (int i = 0; i < 4; i++)
#pragma unroll
    for (int j = 0; j < 4; j++) acc[i][j] = z;

  for (int kt = ks * 32; kt < ks * 32 + 32; kt++) {
    int off = kt * 32;
    __syncthreads();
    stage16(ap[0] + off, la0);
    stage16(ap[1] + off, la1);
    stage16(bp[0] + off, lb0);
    stage16(bp[1] + off, lb1);
    __syncthreads();
    mma_step(lA, lB, acc, lane, wm, wn);
  }

  float* Sp = S + ks * 4194304;
  const int r15 = lane & 15, q4 = lane >> 4;
#pragma unroll
  for (int ni = 0; ni < 4; ni++) {
    int j = jt * 128 + wn * 64 + ni * 16 + r15;
#pragma unroll
    for (int mi = 0; mi < 4; mi++) {
      int m0 = mt * 128 + wm * 64 + mi * 16 + q4 * 4;
#pragma unroll
      for (int r = 0; r < 4; r++)
        Sp[(m0 + r) * 2048 + j] = acc[mi][ni][r];
    }
  }
}

// ---------------- per-row masked softmax over summed K-planes -> P (bf16) ----------------
__global__ void k_softmax(const float* __restrict__ S, const int* __restrict__ gid,
                          const int* __restrict__ seg, unsigned short* __restrict__ P) {
  const int m = blockIdx.x * 4 + (threadIdx.x >> 6);
  const int lane = threadIdx.x & 63;
  const int stride = seg[17];
  const int g = gid[m * stride];
  const int s0 = seg[g], e = seg[g + 1];
  const float scale = 0.04419417382415922f;   // 1/sqrt(512)
  const float* row = S + m * 2048;
  float mx = -3.0e38f;
  for (int j = s0 + lane; j < e; j += 64) {
    float v = row[j] + row[j + 4194304] + row[j + 8388608] + row[j + 12582912];
    mx = fmaxf(mx, v);
  }
#pragma unroll
  for (int off = 32; off > 0; off >>= 1) mx = fmaxf(mx, __shfl_xor(mx, off));
  float sum = 0.f;
  for (int j = s0 + lane; j < e; j += 64) {
    float v = row[j] + row[j + 4194304] + row[j + 8388608] + row[j + 12582912];
    sum += __expf((v - mx) * scale);
  }
#pragma unroll
  for (int off = 32; off > 0; off >>= 1) sum += __shfl_xor(sum, off);
  const float inv = 1.f / sum;
  unsigned short* prow = P + m * 2048;
  for (int j = s0 + lane; j < e; j += 64) {
    float v = row[j] + row[j + 4194304] + row[j + 8388608] + row[j + 12582912];
    prow[j] = f2bf(__expf((v - mx) * scale) * inv);
  }
}

// ---------------- vf [2048][4096] -> vT [4096][2048] ----------------
__global__ void k_transpose_v(const unsigned short* __restrict__ vf,
                              unsigned short* __restrict__ vT) {
  __shared__ unsigned short t[64][66];
  const int jt = blockIdx.x, dt = blockIdx.y;
  const int tid = threadIdx.x;
  const int r = tid >> 6, c = tid & 63;
#pragma unroll
  for (int i = 0; i < 16; i++) {
    int j = i * 4 + r;
    t[j][c] = vf[(jt * 64 + j) * 4096 + dt * 64 + c];
  }
  __syncthreads();
#pragma unroll
  for (int i = 0; i < 16; i++) {
    int d = i * 4 + r;
    vT[(dt * 64 + d) * 2048 + jt * 64 + c] = t[c][d];
  }
}

// ---------------- out = P @ V (ragged K per m-tile), epilogue -> NCHW f32 ----------------
__global__ __launch_bounds__(256, 2) void k_pv(
    const unsigned short* __restrict__ P, const unsigned short* __restrict__ vT,
    const int* __restrict__ gid, const int* __restrict__ seg, float* __restrict__ out) {
  const int mt = blockIdx.x, dt = blockIdx.y;
  const int stride = seg[17];
  const int g_lo = gid[(mt * 128) * stride], g_hi = gid[(mt * 128 + 127) * stride];
  const int ks0 = seg[g_lo] & ~31;
  const int ke = seg[g_hi + 1];
  const int iters = (ke - ks0 + 31) >> 5;   // P==0 outside segments covers padding

  __shared__ __align__(16) unsigned short lA[128 * 32];
  __shared__ __align__(16) unsigned short lB[128 * 32];
  const int tid = threadIdx.x;
  const int wave = tid >> 6, lane = tid & 63;
  const int wm = wave >> 1, wn = wave & 1;
  const int srow = wave * 32 + (lane >> 2);
  const int clog = (lane & 3) ^ ((lane >> 3) & 3);
  const unsigned short* ap[2];
  const unsigned short* bp[2];
#pragma unroll
  for (int h = 0; h < 2; h++) {
    ap[h] = P + (mt * 128 + srow + h * 16) * 2048 + ks0 + clog * 8;
    bp[h] = vT + (dt * 128 + srow + h * 16) * 2048 + ks0 + clog * 8;
  }
  unsigned short* la0 = lA + (wave * 32) * 32;
  unsigned short* la1 = lA + (wave * 32 + 16) * 32;
  unsigned short* lb0 = lB + (wave * 32) * 32;
  unsigned short* lb1 = lB + (wave * 32 + 16) * 32;

  f32x4 acc[4][4];
  const f32x4 z = {0.f, 0.f, 0.f, 0.f};
#pragma unroll
  for (int i = 0; i < 4; i++)
#pragma unroll
    for (int j = 0; j < 4; j++) acc[i][j] = z;

  for (int kt = 0; kt < iters; kt++) {
    int off = kt * 32;
    __syncthreads();
    stage16(ap[0] + off, la0);
    stage16(ap[1] + off, la1);
    stage16(bp[0] + off, lb0);
    stage16(bp[1] + off, lb1);
    __syncthreads();
    mma_step(lA, lB, acc, lane, wm, wn);
  }

  const int r15 = lane & 15, q4 = lane >> 4;
#pragma unroll
  for (int ni = 0; ni < 4; ni++) {
    int d = dt * 128 + wn * 64 + ni * 16 + r15;
    int c = d & 255, pix = d >> 8;   // our d = pix*256 + c; ref wants n*4096 + c*16 + pix
#pragma unroll
    for (int mi = 0; mi < 4; mi++) {
      int m0 = mt * 128 + wm * 64 + mi * 16 + q4 * 4;
#pragma unroll
      for (int r = 0; r < 4; r++)
        out[(m0 + r) * 4096 + c * 16 + pix] = acc[mi][ni][r];
    }
  }
}

extern "C" void kernel_launch(void* const* d_in, const int* in_sizes, int n_in,
                              void* d_out, int out_size, void* d_ws, size_t ws_size,
                              hipStream_t stream) {
  const float* x   = (const float*)d_in[0];
  const int*   gid = (const int*)d_in[1];
  const float* qw1 = (const float*)d_in[2];
  const float* qb1 = (const float*)d_in[3];
  const float* qw2 = (const float*)d_in[4];
  const float* qb2 = (const float*)d_in[5];
  const float* kw1 = (const float*)d_in[6];
  const float* kb1 = (const float*)d_in[7];
  const float* kw2 = (const float*)d_in[8];
  const float* kb2 = (const float*)d_in[9];
  const float* vw1 = (const float*)d_in[10];
  const float* vb1 = (const float*)d_in[11];
  const float* vw2 = (const float*)d_in[12];
  const float* vb2 = (const float*)d_in[13];

  char* ws = (char*)d_ws;
  unsigned short* xb  = (unsigned short*)(ws + XB_OFF);
  unsigned short* w1t = (unsigned short*)(ws + W1_OFF);
  unsigned short* w2t = (unsigned short*)(ws + W2_OFF);
  unsigned short* y1  = (unsigned short*)(ws + Y1_OFF);
  unsigned short* qkv = (unsigned short*)(ws + QKV_OFF);
  int* seg            = (int*)(ws + SEG_OFF);
  float* S            = (float*)(ws + S_OFF);
  unsigned short* P   = (unsigned short*)(ws + P_OFF);
  unsigned short* vT  = (unsigned short*)(ws + VT_OFF);
  const unsigned short* qf = qkv;
  const unsigned short* kf = qkv + 8388608;
  const unsigned short* vf = qkv + 16777216;

  k_seg<<<1, 256, 0, stream>>>(gid, seg);
  k_convert_x<<<dim3(2048, 8), 256, 0, stream>>>(x, xb);
  k_convert_w<<<20736, 256, 0, stream>>>(qw1, kw1, vw1, qw2, kw2, vw2, w1t, w2t);
  k_conv1<<<dim3(576, 6), 256, 0, stream>>>(xb, w1t, qb1, kb1, vb1, y1);
  k_conv2<<<dim3(256, 2, 3), 256, 0, stream>>>(y1, w2t, qb2, kb2, vb2, qkv);
  hipMemsetAsync(P, 0, 8388608, stream);   // P zero outside segments (S/P/vT alias dead y1)
  k_scores<<<dim3(16, 16, 4), 256, 0, stream>>>(qf, kf, gid, seg, S);
  k_softmax<<<512, 256, 0, stream>>>(S, gid, seg, P);
  k_transpose_v<<<dim3(32, 64), 256, 0, stream>>>(vf, vT);
  k_pv<<<dim3(16, 32), 256, 0, stream>>>(P, vT, gid, seg, (float*)d_out);
}

// Round 3
// 1321.865 us; speedup vs baseline: 1.0910x; 1.0482x over previous
//
#include <hip/hip_runtime.h>
#include <hip/hip_bf16.h>

#define DI __device__ __forceinline__

typedef float f32x4 __attribute__((ext_vector_type(4)));
typedef __bf16 bf16x8 __attribute__((ext_vector_type(8)));

// ---------------- workspace layout (bytes) ----------------
#define XB_OFF   0ll                      // [2048][8][8][512] bf16  = 134217728
#define W1_OFF   134217728ll              // [768][4608] bf16        = 7077888
#define W2_OFF   141295616ll              // [768][2304] bf16        = 3538944
#define Y1_OFF   144834560ll              // [73728][768] bf16       = 113246208
#define QKV_OFF  258080768ll              // 3 x [32768][256] bf16   = 50331648
#define SEG_OFF  308412416ll              // 18 ints
// aliases inside the Y1 region (only used after conv2 is done):
#define S_OFF    (Y1_OFF)                 // 4 x [2048][2048] f32 = 67108864
#define P_OFF    (Y1_OFF + 67108864ll)    // [2048][2048] bf16    = 8388608
#define VT_OFF   (Y1_OFF + 75497472ll)    // [4096][2048] bf16    = 16777216

DI unsigned short f2bf(float f) {
  union { float f; unsigned u; } v; v.f = f;
  return (unsigned short)((v.u + 0x7FFFu + ((v.u >> 16) & 1u)) >> 16);
}

// async global->LDS, 16B per lane; LDS dest is wave-uniform base + lane*16
DI void stage16(const void* g, void* l) {
  __builtin_amdgcn_global_load_lds(
      (const __attribute__((address_space(1))) void*)(unsigned long long)g,
      (__attribute__((address_space(3))) void*)(unsigned long long)l,
      16, 0, 0);
}

// BK=64 LDS tile: [128 rows][8 chunks of 16B]; row stride = 128 B = full 32-bank span,
// so bank group depends only on chunk. Phys chunk = logical ^ (row&7):
//  - read: quarter-wave (16 lanes, rows 0..15, same logical chunk) spreads over
//    8 bank groups 2-way -> free (m136).
//  - staging lane l covers row (l>>3), phys chunk (l&7) -> clog=(l&7)^((l>>3)&7).
DI void mma_step64(const unsigned short* lA, const unsigned short* lB,
                   f32x4 acc[4][4], int lane, int wm, int wn) {
  const int r15 = lane & 15;
  const int cb = lane >> 4;            // k-subchunk within a 32-wide half
  const int rx = r15 & 7;
#pragma unroll
  for (int kh = 0; kh < 2; kh++) {
    const int ph = (kh * 4 + cb) ^ rx;
    bf16x8 af[4], bfr[4];
#pragma unroll
    for (int mi = 0; mi < 4; mi++)
      af[mi] = *(const bf16x8*)(lA + (wm * 64 + mi * 16 + r15) * 64 + ph * 8);
#pragma unroll
    for (int ni = 0; ni < 4; ni++)
      bfr[ni] = *(const bf16x8*)(lB + (wn * 64 + ni * 16 + r15) * 64 + ph * 8);
#pragma unroll
    for (int mi = 0; mi < 4; mi++)
#pragma unroll
      for (int ni = 0; ni < 4; ni++)
        acc[mi][ni] = __builtin_amdgcn_mfma_f32_16x16x32_bf16(af[mi], bfr[ni], acc[mi][ni], 0, 0, 0);
  }
}

// ---------------- segment offsets (+ int32/int64 layout detect) ----------------
__global__ void k_seg(const int* __restrict__ gid, int* __restrict__ seg) {
  __shared__ int cnt[16];
  int tid = threadIdx.x;
  if (tid < 16) cnt[tid] = 0;
  __syncthreads();
  int stride = (gid[2047] == 0) ? 2 : 1;
  for (int i = tid; i < 2048; i += 256) atomicAdd(&cnt[gid[i * stride]], 1);
  __syncthreads();
  if (tid == 0) {
    int s = 0;
    for (int g = 0; g < 16; g++) { seg[g] = s; s += cnt[g]; }
    seg[16] = s;
    seg[17] = stride;
  }
}

// ---------------- NCHW f32 -> NHWC bf16 ----------------
__global__ void k_convert_x(const float* __restrict__ x, unsigned short* __restrict__ xb) {
  __shared__ unsigned short t[64][66];   // [pixel][channel]
  const int n = blockIdx.x, cb = blockIdx.y;
  const int tid = threadIdx.x;
  const int cr = tid >> 6, p = tid & 63;
  const float* src = x + (n * 512 + cb * 64) * 64;
#pragma unroll
  for (int i = 0; i < 16; i++) {
    int c = i * 4 + cr;
    t[p][c] = f2bf(src[c * 64 + p]);
  }
  __syncthreads();
  unsigned* dst = (unsigned*)(xb + n * 32768 + cb * 64);
  const int pr = tid >> 5, c2 = tid & 31;
#pragma unroll
  for (int i = 0; i < 8; i++) {
    int p2 = i * 8 + pr;
    unsigned lo = t[p2][c2 * 2], hi = t[p2][c2 * 2 + 1];
    dst[p2 * 256 + c2] = lo | (hi << 16);
  }
}

// ---------------- weights: OIHW f32 -> [row][(ky,kx,cin)] bf16, fused w1+w2 ----------------
__global__ void k_convert_w(const float* __restrict__ qw1, const float* __restrict__ kw1,
                            const float* __restrict__ vw1, const float* __restrict__ qw2,
                            const float* __restrict__ kw2, const float* __restrict__ vw2,
                            unsigned short* __restrict__ w1t, unsigned short* __restrict__ w2t) {
  int idx = blockIdx.x * 256 + threadIdx.x;
  if (idx < 3538944) {                       // w1: 768 x 4608
    int row = idx / 4608, k = idx - row * 4608;
    int br = row >> 8, o = row & 255;
    int kk = k >> 9, cin = k & 511;
    int ky = kk / 3, kx = kk - ky * 3;
    const float* w = (br == 0) ? qw1 : (br == 1) ? kw1 : vw1;
    w1t[idx] = f2bf(w[((o * 512 + cin) * 3 + ky) * 3 + kx]);
  } else {                                   // w2: 768 x 2304
    idx -= 3538944;
    int row = idx / 2304, k = idx - row * 2304;
    int br = row >> 8, o = row & 255;
    int kk = k >> 8, c = k & 255;
    int ky = kk / 3, kx = kk - ky * 3;
    const float* w = (br == 0) ? qw2 : (br == 1) ? kw2 : vw2;
    w2t[idx] = f2bf(w[((o * 256 + c) * 3 + ky) * 3 + kx]);
  }
}

// ---------------- conv1 implicit GEMM: M=73728 K=4608 N=768, BK=64 ----------------
// grid (nt=6 fast, mt=576): 6 consecutive blocks share one A-tile -> L2/L3 resident A.
__global__ __launch_bounds__(256, 2) void k_conv1(
    const unsigned short* __restrict__ xb, const unsigned short* __restrict__ w1t,
    const float* __restrict__ qb1, const float* __restrict__ kb1, const float* __restrict__ vb1,
    unsigned short* __restrict__ y1) {
  __shared__ __align__(16) unsigned short lA[128 * 64];
  __shared__ __align__(16) unsigned short lB[128 * 64];
  const int nt = blockIdx.x, mt = blockIdx.y;
  const int tid = threadIdx.x;
  const int wave = tid >> 6, lane = tid & 63;
  const int wm = wave >> 1, wn = wave & 1;

  const int clog = (lane & 7) ^ ((lane >> 3) & 7);
  const unsigned short* ap[4];
  const unsigned short* bp[4];
#pragma unroll
  for (int s = 0; s < 4; s++) {
    int m = mt * 128 + wave * 32 + s * 8 + (lane >> 3);
    int n = m / 36, pix = m - n * 36;
    int oy = pix / 6, ox = pix - oy * 6;
    ap[s] = xb + ((n * 8 + oy) * 8 + ox) * 512 + clog * 8;
    int r = nt * 128 + wave * 32 + s * 8 + (lane >> 3);
    bp[s] = w1t + r * 4608 + clog * 8;
  }

  f32x4 acc[4][4];
  const f32x4 z = {0.f, 0.f, 0.f, 0.f};
#pragma unroll
  for (int i = 0; i < 4; i++)
#pragma unroll
    for (int j = 0; j < 4; j++) acc[i][j] = z;

  for (int kt = 0; kt < 72; kt++) {
    int kk = kt >> 3;
    int ky = kk / 3, kx = kk - ky * 3;
    int aoff = (ky * 8 + kx) * 512 + (kt & 7) * 64;
    int boff = kt * 64;
    __syncthreads();
#pragma unroll
    for (int s = 0; s < 4; s++) {
      stage16(ap[s] + aoff, lA + (wave * 32 + s * 8) * 64);
      stage16(bp[s] + boff, lB + (wave * 32 + s * 8) * 64);
    }
    __syncthreads();
    mma_step64(lA, lB, acc, lane, wm, wn);
  }

  const float* bias = (nt < 2) ? qb1 : (nt < 4) ? kb1 : vb1;
  const int r15 = lane & 15, q4 = lane >> 4;
#pragma unroll
  for (int ni = 0; ni < 4; ni++) {
    int col = nt * 128 + wn * 64 + ni * 16 + r15;
    float bv = bias[col & 255];
#pragma unroll
    for (int mi = 0; mi < 4; mi++) {
      int m0 = mt * 128 + wm * 64 + mi * 16 + q4 * 4;
#pragma unroll
      for (int r = 0; r < 4; r++) {
        float v = acc[mi][ni][r] + bv;
        y1[(m0 + r) * 768 + col] = f2bf(v > 0.f ? v : 0.f);
      }
    }
  }
}

// ---------------- conv2 implicit GEMM per branch: M=32768 K=2304 N=256, BK=64 ----------------
// grid (nt=2 fast, br=3, mt=256): 6 consecutive blocks share one A-tile.
__global__ __launch_bounds__(256, 2) void k_conv2(
    const unsigned short* __restrict__ y1, const unsigned short* __restrict__ w2t,
    const float* __restrict__ qb2, const float* __restrict__ kb2, const float* __restrict__ vb2,
    unsigned short* __restrict__ qkv) {
  __shared__ __align__(16) unsigned short lA[128 * 64];
  __shared__ __align__(16) unsigned short lB[128 * 64];
  const int nt = blockIdx.x, br = blockIdx.y, mt = blockIdx.z;
  const int tid = threadIdx.x;
  const int wave = tid >> 6, lane = tid & 63;
  const int wm = wave >> 1, wn = wave & 1;

  const int clog = (lane & 7) ^ ((lane >> 3) & 7);
  const unsigned short* ap[4];
  const unsigned short* bp[4];
#pragma unroll
  for (int s = 0; s < 4; s++) {
    int m = mt * 128 + wave * 32 + s * 8 + (lane >> 3);
    int n = m >> 4, pix = m & 15;
    int oy = pix >> 2, ox = pix & 3;
    ap[s] = y1 + (n * 36 + oy * 6 + ox) * 768 + br * 256 + clog * 8;
    int r = br * 256 + nt * 128 + wave * 32 + s * 8 + (lane >> 3);
    bp[s] = w2t + r * 2304 + clog * 8;
  }

  f32x4 acc[4][4];
  const f32x4 z = {0.f, 0.f, 0.f, 0.f};
#pragma unroll
  for (int i = 0; i < 4; i++)
#pragma unroll
    for (int j = 0; j < 4; j++) acc[i][j] = z;

  for (int kt = 0; kt < 36; kt++) {
    int kk = kt >> 2;
    int ky = kk / 3, kx = kk - ky * 3;
    int aoff = (ky * 6 + kx) * 768 + (kt & 3) * 64;
    int boff = kt * 64;
    __syncthreads();
#pragma unroll
    for (int s = 0; s < 4; s++) {
      stage16(ap[s] + aoff, lA + (wave * 32 + s * 8) * 64);
      stage16(bp[s] + boff, lB + (wave * 32 + s * 8) * 64);
    }
    __syncthreads();
    mma_step64(lA, lB, acc, lane, wm, wn);
  }

  const float* bias = (br == 0) ? qb2 : (br == 1) ? kb2 : vb2;
  unsigned short* outb = qkv + br * 8388608;
  const int r15 = lane & 15, q4 = lane >> 4;
#pragma unroll
  for (int ni = 0; ni < 4; ni++) {
    int o = nt * 128 + wn * 64 + ni * 16 + r15;
    float bv = bias[o];
#pragma unroll
    for (int mi = 0; mi < 4; mi++) {
      int m0 = mt * 128 + wm * 64 + mi * 16 + q4 * 4;
#pragma unroll
      for (int r = 0; r < 4; r++) {
        float v = acc[mi][ni][r] + bv;
        outb[(m0 + r) * 256 + o] = f2bf(v > 0.f ? v : 0.f);
      }
    }
  }
}

// ---------------- S_part[ks] = Q @ K^T over K-chunk ks (4-way K-split), BK=64 ----------------
__global__ __launch_bounds__(256, 2) void k_scores(
    const unsigned short* __restrict__ qf, const unsigned short* __restrict__ kf,
    const int* __restrict__ gid, const int* __restrict__ seg, float* __restrict__ S) {
  const int mt = blockIdx.x, jt = blockIdx.y, ks = blockIdx.z;
  const int stride = seg[17];
  const int g_lo = gid[(mt * 128) * stride], g_hi = gid[(mt * 128 + 127) * stride];
  const int jlo = seg[g_lo], jhi = seg[g_hi + 1];
  if (jt * 128 >= jhi || jt * 128 + 128 <= jlo) return;

  __shared__ __align__(16) unsigned short lA[128 * 64];
  __shared__ __align__(16) unsigned short lB[128 * 64];
  const int tid = threadIdx.x;
  const int wave = tid >> 6, lane = tid & 63;
  const int wm = wave >> 1, wn = wave & 1;
  const int clog = (lane & 7) ^ ((lane >> 3) & 7);
  const unsigned short* ap[4];
  const unsigned short* bp[4];
#pragma unroll
  for (int s = 0; s < 4; s++) {
    int row = wave * 32 + s * 8 + (lane >> 3);
    ap[s] = qf + (mt * 128 + row) * 4096 + ks * 1024 + clog * 8;
    bp[s] = kf + (jt * 128 + row) * 4096 + ks * 1024 + clog * 8;
  }

  f32x4 acc[4][4];
  const f32x4 z = {0.f, 0.f, 0.f, 0.f};
#pragma unroll
  for (int i = 0; i < 4; i++)
#pragma unroll
    for (int j = 0; j < 4; j++) acc[i][j] = z;

  for (int kt = 0; kt < 16; kt++) {
    int off = kt * 64;
    __syncthreads();
#pragma unroll
    for (int s = 0; s < 4; s++) {
      stage16(ap[s] + off, lA + (wave * 32 + s * 8) * 64);
      stage16(bp[s] + off, lB + (wave * 32 + s * 8) * 64);
    }
    __syncthreads();
    mma_step64(lA, lB, acc, lane, wm, wn);
  }

  float* Sp = S + ks * 4194304;
  const int r15 = lane & 15, q4 = lane >> 4;
#pragma unroll
  for (int ni = 0; ni < 4; ni++) {
    int j = jt * 128 + wn * 64 + ni * 16 + r15;
#pragma unroll
    for (int mi = 0; mi < 4; mi++) {
      int m0 = mt * 128 + wm * 64 + mi * 16 + q4 * 4;
#pragma unroll
      for (int r = 0; r < 4; r++)
        Sp[(m0 + r) * 2048 + j] = acc[mi][ni][r];
    }
  }
}

// ---------------- per-row masked softmax over summed K-planes -> P (bf16) ----------------
__global__ void k_softmax(const float* __restrict__ S, const int* __restrict__ gid,
                          const int* __restrict__ seg, unsigned short* __restrict__ P) {
  const int m = blockIdx.x * 4 + (threadIdx.x >> 6);
  const int lane = threadIdx.x & 63;
  const int stride = seg[17];
  const int g = gid[m * stride];
  const int s0 = seg[g], e = seg[g + 1];
  const float scale = 0.04419417382415922f;   // 1/sqrt(512)
  const float* row = S + m * 2048;
  float mx = -3.0e38f;
  for (int j = s0 + lane; j < e; j += 64) {
    float v = row[j] + row[j + 4194304] + row[j + 8388608] + row[j + 12582912];
    mx = fmaxf(mx, v);
  }
#pragma unroll
  for (int off = 32; off > 0; off >>= 1) mx = fmaxf(mx, __shfl_xor(mx, off));
  float sum = 0.f;
  for (int j = s0 + lane; j < e; j += 64) {
    float v = row[j] + row[j + 4194304] + row[j + 8388608] + row[j + 12582912];
    sum += __expf((v - mx) * scale);
  }
#pragma unroll
  for (int off = 32; off > 0; off >>= 1) sum += __shfl_xor(sum, off);
  const float inv = 1.f / sum;
  unsigned short* prow = P + m * 2048;
  for (int j = s0 + lane; j < e; j += 64) {
    float v = row[j] + row[j + 4194304] + row[j + 8388608] + row[j + 12582912];
    prow[j] = f2bf(__expf((v - mx) * scale) * inv);
  }
}

// ---------------- vf [2048][4096] -> vT [4096][2048] ----------------
__global__ void k_transpose_v(const unsigned short* __restrict__ vf,
                              unsigned short* __restrict__ vT) {
  __shared__ unsigned short t[64][66];
  const int jt = blockIdx.x, dt = blockIdx.y;
  const int tid = threadIdx.x;
  const int r = tid >> 6, c = tid & 63;
#pragma unroll
  for (int i = 0; i < 16; i++) {
    int j = i * 4 + r;
    t[j][c] = vf[(jt * 64 + j) * 4096 + dt * 64 + c];
  }
  __syncthreads();
#pragma unroll
  for (int i = 0; i < 16; i++) {
    int d = i * 4 + r;
    vT[(dt * 64 + d) * 2048 + jt * 64 + c] = t[c][d];
  }
}

// ---------------- out = P @ V (ragged K per m-tile), BK=64, epilogue -> NCHW f32 ----------------
__global__ __launch_bounds__(256, 2) void k_pv(
    const unsigned short* __restrict__ P, const unsigned short* __restrict__ vT,
    const int* __restrict__ gid, const int* __restrict__ seg, float* __restrict__ out) {
  const int mt = blockIdx.x, dt = blockIdx.y;
  const int stride = seg[17];
  const int g_lo = gid[(mt * 128) * stride], g_hi = gid[(mt * 128 + 127) * stride];
  const int ks0 = seg[g_lo] & ~63;
  const int ke = seg[g_hi + 1];
  const int iters = (ke - ks0 + 63) >> 6;   // P==0 outside segments covers padding

  __shared__ __align__(16) unsigned short lA[128 * 64];
  __shared__ __align__(16) unsigned short lB[128 * 64];
  const int tid = threadIdx.x;
  const int wave = tid >> 6, lane = tid & 63;
  const int wm = wave >> 1, wn = wave & 1;
  const int clog = (lane & 7) ^ ((lane >> 3) & 7);
  const unsigned short* ap[4];
  const unsigned short* bp[4];
#pragma unroll
  for (int s = 0; s < 4; s++) {
    int row = wave * 32 + s * 8 + (lane >> 3);
    ap[s] = P + (mt * 128 + row) * 2048 + ks0 + clog * 8;
    bp[s] = vT + (dt * 128 + row) * 2048 + ks0 + clog * 8;
  }

  f32x4 acc[4][4];
  const f32x4 z = {0.f, 0.f, 0.f, 0.f};
#pragma unroll
  for (int i = 0; i < 4; i++)
#pragma unroll
    for (int j = 0; j < 4; j++) acc[i][j] = z;

  for (int kt = 0; kt < iters; kt++) {
    int off = kt * 64;
    __syncthreads();
#pragma unroll
    for (int s = 0; s < 4; s++) {
      stage16(ap[s] + off, lA + (wave * 32 + s * 8) * 64);
      stage16(bp[s] + off, lB + (wave * 32 + s * 8) * 64);
    }
    __syncthreads();
    mma_step64(lA, lB, acc, lane, wm, wn);
  }

  const int r15 = lane & 15, q4 = lane >> 4;
#pragma unroll
  for (int ni = 0; ni < 4; ni++) {
    int d = dt * 128 + wn * 64 + ni * 16 + r15;
    int c = d & 255, pix = d >> 8;   // our d = pix*256 + c; ref wants n*4096 + c*16 + pix
#pragma unroll
    for (int mi = 0; mi < 4; mi++) {
      int m0 = mt * 128 + wm * 64 + mi * 16 + q4 * 4;
#pragma unroll
      for (int r = 0; r < 4; r++)
        out[(m0 + r) * 4096 + c * 16 + pix] = acc[mi][ni][r];
    }
  }
}

extern "C" void kernel_launch(void* const* d_in, const int* in_sizes, int n_in,
                              void* d_out, int out_size, void* d_ws, size_t ws_size,
                              hipStream_t stream) {
  const float* x   = (const float*)d_in[0];
  const int*   gid = (const int*)d_in[1];
  const float* qw1 = (const float*)d_in[2];
  const float* qb1 = (const float*)d_in[3];
  const float* qw2 = (const float*)d_in[4];
  const float* qb2 = (const float*)d_in[5];
  const float* kw1 = (const float*)d_in[6];
  const float* kb1 = (const float*)d_in[7];
  const float* kw2 = (const float*)d_in[8];
  const float* kb2 = (const float*)d_in[9];
  const float* vw1 = (const float*)d_in[10];
  const float* vb1 = (const float*)d_in[11];
  const float* vw2 = (const float*)d_in[12];
  const float* vb2 = (const float*)d_in[13];

  char* ws = (char*)d_ws;
  unsigned short* xb  = (unsigned short*)(ws + XB_OFF);
  unsigned short* w1t = (unsigned short*)(ws + W1_OFF);
  unsigned short* w2t = (unsigned short*)(ws + W2_OFF);
  unsigned short* y1  = (unsigned short*)(ws + Y1_OFF);
  unsigned short* qkv = (unsigned short*)(ws + QKV_OFF);
  int* seg            = (int*)(ws + SEG_OFF);
  float* S            = (float*)(ws + S_OFF);
  unsigned short* P   = (unsigned short*)(ws + P_OFF);
  unsigned short* vT  = (unsigned short*)(ws + VT_OFF);
  const unsigned short* qf = qkv;
  const unsigned short* kf = qkv + 8388608;
  const unsigned short* vf = qkv + 16777216;

  k_seg<<<1, 256, 0, stream>>>(gid, seg);
  k_convert_x<<<dim3(2048, 8), 256, 0, stream>>>(x, xb);
  k_convert_w<<<20736, 256, 0, stream>>>(qw1, kw1, vw1, qw2, kw2, vw2, w1t, w2t);
  k_conv1<<<dim3(6, 576), 256, 0, stream>>>(xb, w1t, qb1, kb1, vb1, y1);
  k_conv2<<<dim3(2, 3, 256), 256, 0, stream>>>(y1, w2t, qb2, kb2, vb2, qkv);
  hipMemsetAsync(P, 0, 8388608, stream);   // P zero outside segments (S/P/vT alias dead y1)
  k_scores<<<dim3(16, 16, 4), 256, 0, stream>>>(qf, kf, gid, seg, S);
  k_softmax<<<512, 256, 0, stream>>>(S, gid, seg, P);
  k_transpose_v<<<dim3(32, 64), 256, 0, stream>>>(vf, vT);
  k_pv<<<dim3(16, 32), 256, 0, stream>>>(P, vT, gid, seg, (float*)d_out);
}